// Round 1
// 129.053 us; speedup vs baseline: 1.1109x; 1.1109x over previous
//
#include <hip/hip_runtime.h>
#include <hip/hip_bf16.h>

// Conv2dWithLoRA: out = conv3x3(x, W_eff) + b, where W_eff = W + 2.0 * B@A.
// LoRA folded into weights -> single implicit-GEMM conv, bf16 MFMA, fp32 accum.
// M = 16*64*64 = 65536 pixels, N = 256 outs, K = 128*9 = 1152 (18 chunks of 64).
// R1: BK=64 + XOR-swizzled LDS (conflict-free ds_read_b128), halo fused in pad.
// R2: fix LDS row stride in fragment reads.
// R3 (this round):
//   - conv: 256(pix)x256(o) tile, 512 thr / 8 waves (2o x 4pix), per-wave
//     128x64 output. Depth-1 LDS double-buffer (128 KB), raw s_barrier +
//     late-bound vmcnt(0): stage chunk t+1 issued BEFORE compute of chunk t,
//     waited one full chunk later -> loads always in flight, no fresh drain.
//     18 barriers total (was 36), LDS-read bytes/FLOP cut 2.7x.
//   - pad_x + prep_w fused into one launch; pad transpose-read XOR-swizzled
//     (8-way -> 2-way bank conflict).

#define CIN   128
#define COUT  256
#define NBAT  16
#define HPAD  66
#define WPAD  66

typedef __bf16 bf16x8 __attribute__((ext_vector_type(8)));
typedef float f32x4 __attribute__((ext_vector_type(4)));

#define XPAD_ELEMS ((size_t)NBAT * HPAD * WPAD * CIN)   // 8,921,088
#define XPAD_BYTES (XPAD_ELEMS * 2)                      // 17,842,176
#define WT_ELEMS   ((size_t)9 * COUT * CIN)              // 294,912
#define WS_NEED    (XPAD_BYTES + WT_ELEMS * 2)

typedef __attribute__((address_space(1))) void gvoid;
typedef __attribute__((address_space(3))) void lvoid;

__device__ __forceinline__ void load_lds16(const void* g, void* l) {
    // async global->LDS, 16B per lane; LDS dest = wave-uniform base + lane*16
    __builtin_amdgcn_global_load_lds((gvoid*)g, (lvoid*)l, 16, 0, 0);
}

// ---------------------------------------------------------------------------
// Fused pre-kernel: blocks [0,1024) = pad_x, blocks [1024,1152) = prep_w.
//
// pad_x: NCHW fp32 -> NHWC bf16 with +1 zero halo. One block per (n, row h).
//   LDS transpose tile with XOR swizzle on the w index: read phase
//   tile[c0+j][w] was an 8-way bank conflict (lanes stride 8 rows, row
//   stride 66 -> banks repeat); w ^= ((c>>3)&7)<<2 spreads to 2-way (free).
// prep_w: W_eff = W + 2*B@A, cast bf16, layout Wt[tap][o][c] (c contig).
__global__ void pad_prep(const float* __restrict__ x, __bf16* __restrict__ xpad,
                         const float* __restrict__ W, const float* __restrict__ lA,
                         const float* __restrict__ lB, __hip_bfloat16* __restrict__ Wt) {
    __shared__ float tile[128][66];
    const int t = threadIdx.x;

    if (blockIdx.x >= 1024) {
        // ---- prep_w: 128 blocks, each thread owns one (o,c), loops 9 taps
        const int idx = (blockIdx.x - 1024) * 256 + t;   // o*128 + c
        const int c = idx & 127;
        const int o = idx >> 7;
        float lb[8];
#pragma unroll
        for (int r = 0; r < 8; ++r) lb[r] = lB[o * 8 + r];
#pragma unroll
        for (int tap = 0; tap < 9; ++tap) {
            float acc = W[(o * 128 + c) * 9 + tap];
            float s = 0.f;
#pragma unroll
            for (int r = 0; r < 8; ++r)
                s += lb[r] * lA[r * 1152 + c * 9 + tap];
            Wt[tap * 32768 + idx] = __float2bfloat16(acc + 2.0f * s);
        }
        return;
    }

    // ---- pad_x
    const int n = blockIdx.x >> 6;
    const int h = blockIdx.x & 63;
    const float* src = x + (size_t)n * 128 * 4096 + (size_t)h * 64;
#pragma unroll
    for (int i = 0; i < 8; ++i) {                      // 2048 float4 total
        int g  = i * 256 + t;
        int c  = g >> 4;
        int w4 = (g & 15) * 4;
        const float4 v = *reinterpret_cast<const float4*>(src + (size_t)c * 4096 + w4);
        const int wb = w4 ^ (((c >> 3) & 7) << 2);     // swizzle (bits 2..4)
        tile[c][wb + 0] = v.x; tile[c][wb + 1] = v.y;
        tile[c][wb + 2] = v.z; tile[c][wb + 3] = v.w;
    }
    __syncthreads();
    __bf16* dst = xpad + ((size_t)(n * 66 + h + 1) * 66 + 1) * 128;
#pragma unroll
    for (int i = 0; i < 4; ++i) {                      // 64w x 128c bf16 = 16KB
        int g  = i * 256 + t;
        int w  = g >> 4;
        int c0 = (g & 15) * 8;
        const int swr = ((c0 >> 3) & 7) << 2;          // (c0+j)>>3 == c0>>3, j<8
        bf16x8 v;
#pragma unroll
        for (int j = 0; j < 8; ++j) v[j] = (__bf16)tile[c0 + j][w ^ swr];
        *reinterpret_cast<bf16x8*>(dst + (size_t)w * 128 + c0) = v;
    }
    // halo: left/right pixel of this padded row
    bf16x8 z = {};
    __bf16* rowbase = xpad + (size_t)(n * 66 + h + 1) * 66 * 128;
    if (t < 32) {
        int ww = (t < 16) ? 0 : 65;
        int c0 = (t & 15) * 8;
        *reinterpret_cast<bf16x8*>(rowbase + (size_t)ww * 128 + c0) = z;
    }
    // top/bottom halo rows (full 66 px)
    if (h == 0 || h == 63) {
        __bf16* hrow = xpad + (size_t)(n * 66 + (h == 0 ? 0 : 65)) * 66 * 128;
        for (int i = t; i < 66 * 16; i += 256)
            *reinterpret_cast<bf16x8*>(hrow + (size_t)i * 8) = z;
    }
}

// ---------------------------------------------------------------------------
// Main kernel: implicit-GEMM conv. Tile 256(o) x 256(pix), BK=64, 8 waves,
// depth-1 double-buffered pipeline.
//
// LDS map (bf16 elems): A buf0 [0,16K) A buf1 [16K,32K)
//                       B buf0 [32K,48K) B buf1 [48K,64K)   = 128 KiB total.
// Chunk t lives in buf (t&1). Per iteration:
//   vmcnt(0)+lgkmcnt(0) (waits chunk-t loads issued LAST iter -> cheap),
//   raw s_barrier, issue stage(t+1 -> other buf), compute chunk t.
// Stage never targets the buffer being read; reads of the buffer it targets
// finished before the barrier (lgkmcnt fence + program order) -> race-free.
//
// XOR swizzle: physical 16B chunk of logical (row, q) is q^(row&7); inverse
// applied on the per-lane GLOBAL address (swz), LDS dest stays linear.
__global__ void __launch_bounds__(512, 2) conv_mfma(
    const __bf16* __restrict__ xpad, const __bf16* __restrict__ Wt,
    const float* __restrict__ bias, float* __restrict__ out) {
    __shared__ __align__(16) __bf16 lds[65536];        // 128 KiB

    const int tid  = threadIdx.x;
    const int wv   = tid >> 6;                         // 0..7
    const int lane = tid & 63;

    const int n  = blockIdx.x >> 4;                    // 16 tiles per image
    const int h0 = (blockIdx.x & 15) << 2;             // 4 output rows per tile

    // per-lane swizzled source offset (elements), shared by A and B staging:
    // row-within-8 = lane>>3, logical chunk = (lane&7) ^ (lane>>3)
    const int swz = ((lane >> 3) << 7) + ((((lane & 7) ^ (lane >> 3)) & 7) << 3);

    const __bf16* aG[4];
    const __bf16* bG[4];
#pragma unroll
    for (int j = 0; j < 4; ++j) {
        const int r0 = wv * 32 + j * 8;                // first row of this instr
        aG[j] = Wt + (size_t)r0 * 128 + swz;
        bG[j] = xpad + (((size_t)(n * 66 + h0 + (r0 >> 6)) * 66 + (r0 & 63)) * 128) + swz;
    }

    const int wo   = (wv >> 2) << 7;                   // o offset: 0 / 128
    const int wpix = (wv & 3) << 6;                    // pix offset: 0/64/128/192
    const int a_rd = (wo + (lane & 15)) << 6;          // LDS row stride 64 elems
    const int b_rd = (wpix + (lane & 15)) << 6;
    int qo[2];
#pragma unroll
    for (int s = 0; s < 2; ++s)
        qo[s] = ((((lane >> 4) + s * 4) ^ (lane & 7)) & 7) << 3;

    f32x4 acc[8][4] = {};

    // prologue: stage chunk 0 -> buf0 (tap 0, cb 0 => global offsets 0)
#pragma unroll
    for (int j = 0; j < 4; ++j) {
        load_lds16(aG[j], lds + (wv * 32 + j * 8) * 64);
        load_lds16(bG[j], lds + 32768 + (wv * 32 + j * 8) * 64);
    }

#pragma unroll
    for (int t = 0; t < 18; ++t) {
        // chunk t's loads were issued a full iteration ago -> near-zero stall.
        asm volatile("s_waitcnt vmcnt(0) lgkmcnt(0)" ::: "memory");
        __builtin_amdgcn_sched_barrier(0);             // rule #18: pin the wait
        __builtin_amdgcn_s_barrier();                  // raw: no compiler drain

        if (t + 1 < 18) {                              // stage chunk t+1
            const int t1   = t + 1;
            const int tap1 = t1 >> 1, cb1 = t1 & 1;
            const int ao = tap1 * 32768 + cb1 * 64;
            const int bo = ((tap1 / 3) * 66 + (tap1 % 3)) * 128 + cb1 * 64;
            __bf16* Ad = lds + (t1 & 1) * 16384;
            __bf16* Bd = lds + 32768 + (t1 & 1) * 16384;
#pragma unroll
            for (int j = 0; j < 4; ++j) {
                load_lds16(aG[j] + ao, Ad + (wv * 32 + j * 8) * 64);
                load_lds16(bG[j] + bo, Bd + (wv * 32 + j * 8) * 64);
            }
        }

        const __bf16* Ab = lds + (t & 1) * 16384 + a_rd;
        const __bf16* Bb = lds + 32768 + (t & 1) * 16384 + b_rd;
#pragma unroll
        for (int s = 0; s < 2; ++s) {
            bf16x8 af[8], bfr[4];
#pragma unroll
            for (int ni = 0; ni < 4; ++ni)
                bfr[ni] = *reinterpret_cast<const bf16x8*>(Bb + (ni << 10) + qo[s]);
#pragma unroll
            for (int mi = 0; mi < 8; ++mi)
                af[mi] = *reinterpret_cast<const bf16x8*>(Ab + (mi << 10) + qo[s]);
            __builtin_amdgcn_s_setprio(1);
#pragma unroll
            for (int mi = 0; mi < 8; ++mi)
#pragma unroll
                for (int ni = 0; ni < 4; ++ni)
                    acc[mi][ni] = __builtin_amdgcn_mfma_f32_16x16x32_bf16(
                        af[mi], bfr[ni], acc[mi][ni], 0, 0, 0);
            __builtin_amdgcn_s_setprio(0);
        }
    }

    // epilogue: D row=(lane>>4)*4+j (o), col=lane&15 (pix); + bias
    const int col  = lane & 15;
    const int orow = (lane >> 4) << 2;
    const int h    = h0 + (wpix >> 6);
#pragma unroll
    for (int mi = 0; mi < 8; ++mi) {
        const int obm = wo + mi * 16 + orow;
#pragma unroll
        for (int j = 0; j < 4; ++j) {
            const int o = obm + j;
            const float bj = bias[o];
            float* orow_ptr = out + (((size_t)n * 256 + o) * 64 + h) * 64;
#pragma unroll
            for (int ni = 0; ni < 4; ++ni)
                orow_ptr[ni * 16 + col] = acc[mi][ni][j] + bj;
        }
    }
}

// ---------------------------------------------------------------------------
// Fallback (only if workspace too small): naive fp32, correct but slow.
__global__ void conv_naive(const float* __restrict__ x, const float* __restrict__ W,
                           const float* __restrict__ b, const float* __restrict__ lA,
                           const float* __restrict__ lB, float* __restrict__ out) {
    int idx = blockIdx.x * 256 + threadIdx.x;          // ((n*256+o)*64+h)*64+w
    int w = idx & 63, h = (idx >> 6) & 63, o = (idx >> 12) & 255, n = idx >> 20;
    float acc = b[o];
    float hr[8] = {0, 0, 0, 0, 0, 0, 0, 0};
    for (int c = 0; c < 128; ++c)
        for (int kh = 0; kh < 3; ++kh) {
            int hy = h + kh - 1;
            if (hy < 0 || hy > 63) continue;
            for (int kw = 0; kw < 3; ++kw) {
                int wx = w + kw - 1;
                if (wx < 0 || wx > 63) continue;
                float xv = x[((n * 128 + c) * 64 + hy) * 64 + wx];
                int ka = c * 9 + kh * 3 + kw;
                acc += W[(o * 128 + c) * 9 + kh * 3 + kw] * xv;
#pragma unroll
                for (int r = 0; r < 8; ++r) hr[r] += lA[r * 1152 + ka] * xv;
            }
        }
    float ls = 0.f;
#pragma unroll
    for (int r = 0; r < 8; ++r) ls += lB[o * 8 + r] * hr[r];
    out[idx] = acc + 2.0f * ls;
}

// ---------------------------------------------------------------------------
extern "C" void kernel_launch(void* const* d_in, const int* in_sizes, int n_in,
                              void* d_out, int out_size, void* d_ws, size_t ws_size,
                              hipStream_t stream) {
    const float* x  = (const float*)d_in[0];
    const float* W  = (const float*)d_in[1];
    const float* b  = (const float*)d_in[2];
    const float* lA = (const float*)d_in[3];
    const float* lB = (const float*)d_in[4];
    float* out = (float*)d_out;

    if (ws_size < WS_NEED) {
        conv_naive<<<out_size / 256, 256, 0, stream>>>(x, W, b, lA, lB, out);
        return;
    }

    __bf16* xpad = (__bf16*)d_ws;
    __hip_bfloat16* Wt = (__hip_bfloat16*)((char*)d_ws + XPAD_BYTES);

    pad_prep<<<1024 + 128, 256, 0, stream>>>(x, xpad, W, lA, lB, Wt);
    conv_mfma<<<256, 512, 0, stream>>>(xpad, (const __bf16*)Wt, b, out);
}